// Round 16
// baseline (358.759 us; speedup 1.0000x reference)
//
#include <hip/hip_runtime.h>
#include <hip/hip_bf16.h>

typedef __hip_bfloat16 bf16;
typedef __bf16 bf16x8 __attribute__((ext_vector_type(8)));
typedef __bf16 bf16x4 __attribute__((ext_vector_type(4)));
typedef float f32x4 __attribute__((ext_vector_type(4)));

static __device__ __forceinline__ f32x4 mfma16(bf16x8 a, bf16x8 b, f32x4 c) {
  return __builtin_amdgcn_mfma_f32_16x16x32_bf16(a, b, c, 0, 0, 0);
}
static __device__ __forceinline__ bf16x8 ld8(const bf16* p) {
  return *reinterpret_cast<const bf16x8*>(p);
}
// raw v_exp_f32 (2^x): skips libm's denorm-guard; flush-to-zero for very
// negative args is exactly right for softmax numerators.
static __device__ __forceinline__ float fexp2(float x) {
#if __has_builtin(__builtin_amdgcn_exp2f)
  return __builtin_amdgcn_exp2f(x);
#else
  return exp2f(x);
#endif
}

typedef __attribute__((address_space(1))) void gvoid;
typedef __attribute__((address_space(3))) void lvoid;
static __device__ __forceinline__ void gl2lds16(const bf16* g, bf16* l) {
  __builtin_amdgcn_global_load_lds((gvoid*)g, (lvoid*)l, 16, 0, 0);
}

#define CC_SCALE 0.18033688011112042f  // (1/8)*log2(e), folded into Wq/bq

// Bank-conflict fix (T2 via pre-swizzled SOURCE, rule #21):
// chunk' = chunk ^ ((row>>1)&3); writer: (lane&3)^((lane>>3)&3); reader: lq^((lr>>1)&3).
// GELU note: erff is FINAL. Three epilogue-GELU variants (R7/R10/R15) all
// inflated VGPR 76->88/92 via interleaved exp live-ranges and lost more to
// occupancy than the VALU saving (R15: VALUBusy 38->25.6 but dur +1.8us).

// ---------------- fused fp32->bf16 cvt + ALL weight transposes, ONE dispatch -------
__global__ __launch_bounds__(256) void cvt_prep(
    const float* __restrict__ x, bf16* __restrict__ xb,
    const float* __restrict__ Wq, const float* __restrict__ Wk,
    const float* __restrict__ Wv, const float* __restrict__ Wo,
    const float* __restrict__ W1, const float* __restrict__ W2,
    const float* __restrict__ bq, float* __restrict__ bqs,
    bf16* __restrict__ Wtqkv, bf16* __restrict__ WtO,
    bf16* __restrict__ Wt1, bf16* __restrict__ Wt2) {
  int blk = blockIdx.x;
  int tx = threadIdx.x, ty = threadIdx.y;
  if (blk < 8192) {
    int t = ty * 32 + tx;
    long i = (long)blk * 256 + t;
    float4 v = reinterpret_cast<const float4*>(x)[i];
    bf16x4 o;
    o[0] = __float2bfloat16(v.x); o[1] = __float2bfloat16(v.y);
    o[2] = __float2bfloat16(v.z); o[3] = __float2bfloat16(v.w);
    reinterpret_cast<bf16x4*>(xb)[i] = o;
    return;
  }
  if (blk == 11264) {  // bq scale tail
    int t = ty * 32 + tx;
    bqs[t] = bq[t] * CC_SCALE;
    bqs[t + 256] = bq[t + 256] * CC_SCALE;
    return;
  }
  int id = blk - 8192;
  const float* in;
  bf16* out;
  int K, N, n0, k0;
  float scl = 1.0f;
  if (id < 1024) {
    int which = id >> 8, t = id & 255;
    K = 512; N = 512;
    n0 = (t & 15) * 32; k0 = (t >> 4) * 32;
    if (which == 0)      { in = Wq; out = Wtqkv; scl = CC_SCALE; }
    else if (which == 1) { in = Wk; out = Wtqkv + (size_t)512 * 512; }
    else if (which == 2) { in = Wv; out = Wtqkv + (size_t)1024 * 512; }
    else                 { in = Wo; out = WtO; }
  } else if (id < 2048) {
    int t = id - 1024;
    in = W1; out = Wt1; K = 512; N = 2048;
    n0 = (t & 63) * 32; k0 = (t >> 6) * 32;
  } else {
    int t = id - 2048;
    in = W2; out = Wt2; K = 2048; N = 512;
    n0 = (t & 15) * 32; k0 = (t >> 4) * 32;
  }
  __shared__ float tile[32][33];
#pragma unroll
  for (int j = 0; j < 32; j += 8)
    tile[ty + j][tx] = in[(long)(k0 + ty + j) * N + n0 + tx];
  __syncthreads();
#pragma unroll
  for (int j = 0; j < 32; j += 8)
    out[(long)(n0 + ty + j) * K + k0 + tx] = __float2bfloat16(tile[tx][ty + j] * scl);
}

// ---------------- standalone kernels (fallback path) ----------------
__global__ __launch_bounds__(256) void cvt_kernel(const float* __restrict__ in,
                                                  bf16* __restrict__ out) {
  long i = (long)blockIdx.x * 256 + threadIdx.x;
  float4 v = reinterpret_cast<const float4*>(in)[i];
  bf16x4 o;
  o[0] = __float2bfloat16(v.x); o[1] = __float2bfloat16(v.y);
  o[2] = __float2bfloat16(v.z); o[3] = __float2bfloat16(v.w);
  reinterpret_cast<bf16x4*>(out)[i] = o;
}

__global__ void prep_weights(const float* __restrict__ Wq, const float* __restrict__ Wk,
                             const float* __restrict__ Wv, const float* __restrict__ Wo,
                             const float* __restrict__ W1, const float* __restrict__ W2,
                             const float* __restrict__ bq, float* __restrict__ bqs,
                             bf16* __restrict__ Wtqkv, bf16* __restrict__ WtO,
                             bf16* __restrict__ Wt1, bf16* __restrict__ Wt2) {
  int id = blockIdx.x;
  int tx = threadIdx.x, ty = threadIdx.y;
  if (id == 0) {
    int t = ty * 32 + tx;
    bqs[t] = bq[t] * CC_SCALE;
    bqs[t + 256] = bq[t + 256] * CC_SCALE;
  }
  const float* in;
  bf16* out;
  int K, N, n0, k0;
  float scl = 1.0f;
  if (id < 1024) {
    int which = id >> 8, t = id & 255;
    K = 512; N = 512;
    n0 = (t & 15) * 32; k0 = (t >> 4) * 32;
    if (which == 0)      { in = Wq; out = Wtqkv; scl = CC_SCALE; }
    else if (which == 1) { in = Wk; out = Wtqkv + (size_t)512 * 512; }
    else if (which == 2) { in = Wv; out = Wtqkv + (size_t)1024 * 512; }
    else                 { in = Wo; out = WtO; }
  } else if (id < 2048) {
    int t = id - 1024;
    in = W1; out = Wt1; K = 512; N = 2048;
    n0 = (t & 63) * 32; k0 = (t >> 6) * 32;
  } else {
    int t = id - 2048;
    in = W2; out = Wt2; K = 2048; N = 512;
    n0 = (t & 15) * 32; k0 = (t >> 4) * 32;
  }
  __shared__ float tile[32][33];
#pragma unroll
  for (int j = 0; j < 32; j += 8)
    tile[ty + j][tx] = in[(long)(k0 + ty + j) * N + n0 + tx];
  __syncthreads();
#pragma unroll
  for (int j = 0; j < 32; j += 8)
    out[(long)(n0 + ty + j) * K + k0 + tx] = __float2bfloat16(tile[tx][ty + j] * scl);
}

// ---------------- 128^2 MFMA GEMM: 3-buffer ring, counted vmcnt, XOR-swizzled LDS --
template <int MODE>
__global__ __launch_bounds__(256) void gemm_kernel(
    const bf16* __restrict__ A, const bf16* __restrict__ Wt,
    const float* __restrict__ b0, const float* __restrict__ b1_,
    const float* __restrict__ b2_, bf16* C0, bf16* C1, bf16* C2,
    int K, int ldc, int mmask, int mshift) {
  __shared__ alignas(16) bf16 As[3][128 * 32];
  __shared__ alignas(16) bf16 Bs[3][128 * 32];
  const int tid = threadIdx.x;
  const int wave = tid >> 6, lane = tid & 63;
  const int lr = lane & 15, lq = lane >> 4;
  const int L = blockIdx.x;
  const int m0 = (L & mmask) * 128, n0 = (L >> mshift) * 128;
  const int wm = (wave >> 1) * 64, wn = (wave & 1) * 64;

  const int srow0 = (wave * 2) * 16 + (lane >> 2);
  const int srow1 = (wave * 2 + 1) * 16 + (lane >> 2);
  const int scol = (((lane & 3) ^ ((lane >> 3) & 3))) * 8;
  const bf16* Ag0 = A + (long)(m0 + srow0) * K + scol;
  const bf16* Ag1 = A + (long)(m0 + srow1) * K + scol;
  const bf16* Bg0 = Wt + (long)(n0 + srow0) * K + scol;
  const bf16* Bg1 = Wt + (long)(n0 + srow1) * K + scol;
  const int so0 = (wave * 2) * 16 * 32;
  const int so1 = (wave * 2 + 1) * 16 * 32;
  const int xr = (lr >> 1) & 3;

  f32x4 acc[4][4] = {};

  auto stage = [&](int k0, int buf) {
    gl2lds16(Ag0 + k0, &As[buf][so0]);
    gl2lds16(Ag1 + k0, &As[buf][so1]);
    gl2lds16(Bg0 + k0, &Bs[buf][so0]);
    gl2lds16(Bg1 + k0, &Bs[buf][so1]);
  };

  stage(0, 0);
  stage(32, 1);

  const int nk = K >> 5;
  int cur = 0, sb = 2;
  for (int t = 0; t < nk; ++t) {
    if (t < nk - 1) {
      asm volatile("s_waitcnt vmcnt(4)" ::: "memory");
    } else {
      asm volatile("s_waitcnt vmcnt(0)" ::: "memory");
    }
    __builtin_amdgcn_s_barrier();
    if (t < nk - 2) stage((t + 2) << 5, sb);

    bf16x8 af[4], bfr[4];
#pragma unroll
    for (int i = 0; i < 4; ++i)
      af[i] = ld8(&As[cur][(wm + i * 16 + lr) * 32 + (lq ^ xr) * 8]);
#pragma unroll
    for (int j = 0; j < 4; ++j)
      bfr[j] = ld8(&Bs[cur][(wn + j * 16 + lr) * 32 + (lq ^ xr) * 8]);
    if constexpr (MODE == 3) {
#pragma unroll
      for (int i = 0; i < 4; ++i)
#pragma unroll
        for (int j = 0; j < 4; ++j) acc[i][j] = mfma16(af[i], bfr[j], acc[i][j]);
    } else {
#pragma unroll
      for (int i = 0; i < 4; ++i)
#pragma unroll
        for (int j = 0; j < 4; ++j) acc[i][j] = mfma16(bfr[j], af[i], acc[i][j]);
    }

    cur = (cur == 2) ? 0 : cur + 1;
    sb = (sb == 2) ? 0 : sb + 1;
  }

  if constexpr (MODE == 3) {
#pragma unroll
    for (int i = 0; i < 4; ++i) {
      int row0 = m0 + wm + i * 16 + lq * 4;
      int bb = row0 >> 10, tok = row0 & 1023;
#pragma unroll
      for (int j = 0; j < 4; ++j) {
        int col = n0 + wn + j * 16 + lr;
        float bv = b0[col];
        int hh = col >> 6, e = col & 63;
        bf16x4 o;
#pragma unroll
        for (int rr = 0; rr < 4; ++rr) o[rr] = __float2bfloat16(acc[i][j][rr] + bv);
        *reinterpret_cast<bf16x4*>(
            &C0[(((long)((bb * 8 + hh) * 64 + e)) << 10) + tok]) = o;
      }
    }
  } else {
    const float* bias = b0;
    bf16* C = C0;
    int cb = n0;
    if (MODE == 2 && n0 >= 512) { bias = b1_; C = C1; cb = n0 - 512; }
#pragma unroll
    for (int i = 0; i < 4; ++i) {
      int row = m0 + wm + i * 16 + lr;
      long rb = (long)row * ldc;
#pragma unroll
      for (int j = 0; j < 4; ++j) {
        int col0 = cb + wn + j * 16 + lq * 4;
        f32x4 bv = *reinterpret_cast<const f32x4*>(&bias[col0]);
        bf16x4 o;
#pragma unroll
        for (int rr = 0; rr < 4; ++rr) {
          float v = acc[i][j][rr] + bv[rr];
          if (MODE == 1) v = 0.5f * v * (1.0f + erff(v * 0.70710678118654752f));
          o[rr] = __float2bfloat16(v);
        }
        *reinterpret_cast<bf16x4*>(&C[rb + col0]) = o;
      }
    }
  }
}

// ---------------- merged QKV: Q/K (swapped) + V (unswapped) in ONE dispatch --------
__global__ __launch_bounds__(256) void gemm_qkv(
    const bf16* __restrict__ A, const bf16* __restrict__ Wqk,
    const bf16* __restrict__ Wv, const float* __restrict__ bqs,
    const float* __restrict__ bk, const float* __restrict__ bv,
    bf16* __restrict__ Qo, bf16* __restrict__ Ko, bf16* __restrict__ Vt) {
  __shared__ alignas(16) bf16 As[3][128 * 32];
  __shared__ alignas(16) bf16 Bs[3][128 * 32];
  const int tid = threadIdx.x;
  const int wave = tid >> 6, lane = tid & 63;
  const int lr = lane & 15, lq = lane >> 4;
  const int L = blockIdx.x;
  const bool vmode = L >= 1024;
  const int Lx = vmode ? L - 1024 : L;
  const bf16* Wt = vmode ? Wv : Wqk;
  const int m0 = (Lx & 127) * 128, n0 = (Lx >> 7) * 128;
  const int wm = (wave >> 1) * 64, wn = (wave & 1) * 64;
  const int K = 512;

  const int srow0 = (wave * 2) * 16 + (lane >> 2);
  const int srow1 = (wave * 2 + 1) * 16 + (lane >> 2);
  const int scol = (((lane & 3) ^ ((lane >> 3) & 3))) * 8;
  const bf16* Ag0 = A + (long)(m0 + srow0) * K + scol;
  const bf16* Ag1 = A + (long)(m0 + srow1) * K + scol;
  const bf16* Bg0 = Wt + (long)(n0 + srow0) * K + scol;
  const bf16* Bg1 = Wt + (long)(n0 + srow1) * K + scol;
  const int so0 = (wave * 2) * 16 * 32;
  const int so1 = (wave * 2 + 1) * 16 * 32;
  const int xr = (lr >> 1) & 3;

  f32x4 acc[4][4] = {};

  auto stage = [&](int k0, int buf) {
    gl2lds16(Ag0 + k0, &As[buf][so0]);
    gl2lds16(Ag1 + k0, &As[buf][so1]);
    gl2lds16(Bg0 + k0, &Bs[buf][so0]);
    gl2lds16(Bg1 + k0, &Bs[buf][so1]);
  };

  stage(0, 0);
  stage(32, 1);

  const int nk = K >> 5;  // 16
  int cur = 0, sb = 2;
  if (!vmode) {
    for (int t = 0; t < nk; ++t) {
      if (t < nk - 1) {
        asm volatile("s_waitcnt vmcnt(4)" ::: "memory");
      } else {
        asm volatile("s_waitcnt vmcnt(0)" ::: "memory");
      }
      __builtin_amdgcn_s_barrier();
      if (t < nk - 2) stage((t + 2) << 5, sb);
      bf16x8 af[4], bfr[4];
#pragma unroll
      for (int i = 0; i < 4; ++i)
        af[i] = ld8(&As[cur][(wm + i * 16 + lr) * 32 + (lq ^ xr) * 8]);
#pragma unroll
      for (int j = 0; j < 4; ++j)
        bfr[j] = ld8(&Bs[cur][(wn + j * 16 + lr) * 32 + (lq ^ xr) * 8]);
#pragma unroll
      for (int i = 0; i < 4; ++i)
#pragma unroll
        for (int j = 0; j < 4; ++j) acc[i][j] = mfma16(bfr[j], af[i], acc[i][j]);
      cur = (cur == 2) ? 0 : cur + 1;
      sb = (sb == 2) ? 0 : sb + 1;
    }
    const float* bias = bqs;
    bf16* C = Qo;
    int cb = n0;
    if (n0 >= 512) { bias = bk; C = Ko; cb = n0 - 512; }
#pragma unroll
    for (int i = 0; i < 4; ++i) {
      int row = m0 + wm + i * 16 + lr;
      long rb = (long)row * 512;
#pragma unroll
      for (int j = 0; j < 4; ++j) {
        int col0 = cb + wn + j * 16 + lq * 4;
        f32x4 bv = *reinterpret_cast<const f32x4*>(&bias[col0]);
        bf16x4 o;
#pragma unroll
        for (int rr = 0; rr < 4; ++rr)
          o[rr] = __float2bfloat16(acc[i][j][rr] + bv[rr]);
        *reinterpret_cast<bf16x4*>(&C[rb + col0]) = o;
      }
    }
  } else {
    for (int t = 0; t < nk; ++t) {
      if (t < nk - 1) {
        asm volatile("s_waitcnt vmcnt(4)" ::: "memory");
      } else {
        asm volatile("s_waitcnt vmcnt(0)" ::: "memory");
      }
      __builtin_amdgcn_s_barrier();
      if (t < nk - 2) stage((t + 2) << 5, sb);
      bf16x8 af[4], bfr[4];
#pragma unroll
      for (int i = 0; i < 4; ++i)
        af[i] = ld8(&As[cur][(wm + i * 16 + lr) * 32 + (lq ^ xr) * 8]);
#pragma unroll
      for (int j = 0; j < 4; ++j)
        bfr[j] = ld8(&Bs[cur][(wn + j * 16 + lr) * 32 + (lq ^ xr) * 8]);
#pragma unroll
      for (int i = 0; i < 4; ++i)
#pragma unroll
        for (int j = 0; j < 4; ++j) acc[i][j] = mfma16(af[i], bfr[j], acc[i][j]);
      cur = (cur == 2) ? 0 : cur + 1;
      sb = (sb == 2) ? 0 : sb + 1;
    }
#pragma unroll
    for (int i = 0; i < 4; ++i) {
      int row0 = m0 + wm + i * 16 + lq * 4;
      int bb = row0 >> 10, tok = row0 & 1023;
#pragma unroll
      for (int j = 0; j < 4; ++j) {
        int col = n0 + wn + j * 16 + lr;
        float bvv = bv[col];
        int hh = col >> 6, e = col & 63;
        bf16x4 o;
#pragma unroll
        for (int rr = 0; rr < 4; ++rr) o[rr] = __float2bfloat16(acc[i][j][rr] + bvv);
        *reinterpret_cast<bf16x4*>(
            &Vt[(((long)((bb * 8 + hh) * 64 + e)) << 10) + tok]) = o;
      }
    }
  }
}

// ---------------- fused flash attention: LDS-staged K/V (swizzled), 32 q/wave ------
__global__ __launch_bounds__(256) void attn_fused(
    const bf16* __restrict__ Q, const bf16* __restrict__ Km,
    const bf16* __restrict__ Vt, bf16* __restrict__ O) {
  constexpr int SP = 72;
  __shared__ alignas(16) bf16 Pall[4][32 * SP];
  __shared__ alignas(16) bf16 Ks[2][2][64][32];
  __shared__ alignas(16) bf16 Vs[2][2][64][32];
  const int tid = threadIdx.x;
  const int wave = tid >> 6, lane = tid & 63;
  const int lr = lane & 15, lq = lane >> 4;
  const int L = blockIdx.x;
  const int bh = ((L >> 6) << 3) | (L & 7);   // same bh -> same XCD
  const int qc = (L >> 3) & 7;
  const int h = bh & 7, b = bh >> 3;
  const int q0 = qc * 128 + wave * 32;
  bf16* P = Pall[wave];

  bf16x8 qf[2][2];
#pragma unroll
  for (int qs = 0; qs < 2; ++qs) {
    const bf16* qrow = Q + (long)(b * 1024 + q0 + qs * 16 + lr) * 512 + h * 64;
    qf[qs][0] = ld8(qrow + lq * 8);
    qf[qs][1] = ld8(qrow + 32 + lq * 8);
  }
  const bf16* kbase = Km + (long)(b * 1024) * 512 + h * 64;
  const bf16* vbase = Vt + (long)((b * 8 + h) * 64) * 1024;

  const int sr = wave * 16 + (lane >> 2);
  const int sc = (((lane & 3) ^ ((lane >> 3) & 3))) * 8;
  const bf16* Kg = kbase + (long)sr * 512 + sc;
  const bf16* Vg = vbase + (long)sr * 1024 + sc;
  const int xr = (lr >> 1) & 3;

  auto stage = [&](int kb, int p) {
#pragma unroll
    for (int kk = 0; kk < 2; ++kk)
      gl2lds16(Kg + (long)kb * 64 * 512 + kk * 32, &Ks[p][kk][wave * 16][0]);
#pragma unroll
    for (int kk = 0; kk < 2; ++kk)
      gl2lds16(Vg + kb * 64 + kk * 32, &Vs[p][kk][wave * 16][0]);
  };

  bf16x8 ones;
#pragma unroll
  for (int k = 0; k < 8; ++k) ones[k] = __float2bfloat16(1.0f);

  f32x4 oacc[2][4] = {};
  f32x4 lacc[2] = {};

  stage(0, 0);
  __syncthreads();

  int p = 0;
  for (int kb = 0; kb < 16; ++kb) {
    if (kb < 15) stage(kb + 1, p ^ 1);  // block-uniform; drained by end barrier
#pragma unroll
    for (int kt = 0; kt < 4; ++kt) {
      bf16x8 kf0 = ld8(&Ks[p][0][kt * 16 + lr][(lq ^ xr) * 8]);
      bf16x8 kf1 = ld8(&Ks[p][1][kt * 16 + lr][(lq ^ xr) * 8]);
#pragma unroll
      for (int qs = 0; qs < 2; ++qs) {
        f32x4 t = {};
        t = mfma16(kf0, qf[qs][0], t);
        t = mfma16(kf1, qf[qs][1], t);
        bf16x4 pk;
#pragma unroll
        for (int rr = 0; rr < 4; ++rr) pk[rr] = __float2bfloat16(fexp2(t[rr]));
        *reinterpret_cast<bf16x4*>(&P[(qs * 16 + lr) * SP + kt * 16 + lq * 4]) = pk;
      }
    }
    __builtin_amdgcn_sched_barrier(0);  // P writes before P reads; caps VGPR
    bf16x8 pf[2][2];
#pragma unroll
    for (int qs = 0; qs < 2; ++qs) {
      pf[qs][0] = ld8(&P[(qs * 16 + lr) * SP + lq * 8]);
      pf[qs][1] = ld8(&P[(qs * 16 + lr) * SP + 32 + lq * 8]);
    }
#pragma unroll
    for (int qs = 0; qs < 2; ++qs) {
      lacc[qs] = mfma16(ones, pf[qs][0], lacc[qs]);   // l(q=lr) in every slot
      lacc[qs] = mfma16(ones, pf[qs][1], lacc[qs]);
    }
#pragma unroll
    for (int j0 = 0; j0 < 4; ++j0) {
      bf16x8 vf0 = ld8(&Vs[p][0][j0 * 16 + lr][(lq ^ xr) * 8]);
      bf16x8 vf1 = ld8(&Vs[p][1][j0 * 16 + lr][(lq ^ xr) * 8]);
#pragma unroll
      for (int qs = 0; qs < 2; ++qs) {
        oacc[qs][j0] = mfma16(vf0, pf[qs][0], oacc[qs][j0]);  // swapped: col=q
        oacc[qs][j0] = mfma16(vf1, pf[qs][1], oacc[qs][j0]);
      }
    }
    __builtin_amdgcn_sched_barrier(0);  // P reads before next iter's P writes
    __syncthreads();  // drains vmcnt: buf p^1 staged; readers of buf p done
    p ^= 1;
  }

  // lane holds O[q = q0+qs*16+lr][e = j0*16 + lq*4 + rr]
#pragma unroll
  for (int qs = 0; qs < 2; ++qs) {
    float lv = 1.0f / lacc[qs][0];
    bf16* orow = O + (long)(b * 1024 + q0 + qs * 16 + lr) * 512 + h * 64 + lq * 4;
#pragma unroll
    for (int j0 = 0; j0 < 4; ++j0) {
      bf16x4 o;
#pragma unroll
      for (int rr = 0; rr < 4; ++rr) o[rr] = __float2bfloat16(oacc[qs][j0][rr] * lv);
      *reinterpret_cast<bf16x4*>(&orow[j0 * 16]) = o;
    }
  }
}

// ---------------- fallback attention (Q pre-scaled) ----------------
__global__ __launch_bounds__(256) void attn_kernel(
    const bf16* Q, const bf16* __restrict__ Km,
    const bf16* __restrict__ Vt, bf16* O) {
  constexpr int SP = 72;
  __shared__ alignas(16) bf16 Pall[4][64 * SP];
  const int tid = threadIdx.x;
  const int wave = tid >> 6, lane = tid & 63;
  const int lr = lane & 15, lq = lane >> 4;
  const int L = blockIdx.x;
  const int bh = ((L >> 5) << 3) | (L & 7);
  const int qc = (L >> 3) & 3;
  const int h = bh & 7, b = bh >> 3;
  const int q0 = qc * 256 + wave * 64;
  bf16* P = Pall[wave];

  bf16x8 qf[4][2];
#pragma unroll
  for (int qs = 0; qs < 4; ++qs) {
    const bf16* qrow = Q + (long)(b * 1024 + q0 + qs * 16 + lr) * 512 + h * 64;
    qf[qs][0] = ld8(qrow + lq * 8);
    qf[qs][1] = ld8(qrow + 32 + lq * 8);
  }
  const bf16* kbase = Km + (long)(b * 1024) * 512 + h * 64;
  const bf16* vbase = Vt + (long)((b * 8 + h) * 64) * 1024;

  bf16x8 ones;
#pragma unroll
  for (int k = 0; k < 8; ++k) ones[k] = __float2bfloat16(1.0f);

  f32x4 oacc[4][4] = {};
  f32x4 lacc[4] = {};

  for (int kb = 0; kb < 16; ++kb) {
#pragma unroll
    for (int kt = 0; kt < 4; ++kt) {
      const bf16* krow = kbase + (long)(kb * 64 + kt * 16 + lr) * 512;
      bf16x8 kf0 = ld8(krow + lq * 8);
      bf16x8 kf1 = ld8(krow + 32 + lq * 8);
#pragma unroll
      for (int qs = 0; qs < 4; ++qs) {
        f32x4 t = {};
        t = mfma16(kf0, qf[qs][0], t);
        t = mfma16(kf1, qf[qs][1], t);
        bf16x4 pk;
#pragma unroll
        for (int rr = 0; rr < 4; ++rr) pk[rr] = __float2bfloat16(fexp2(t[rr]));
        *reinterpret_cast<bf16x4*>(&P[(qs * 16 + lr) * SP + kt * 16 + lq * 4]) = pk;
      }
    }
    __builtin_amdgcn_sched_barrier(0);
    bf16x8 pf[4][2];
#pragma unroll
    for (int qs = 0; qs < 4; ++qs) {
      pf[qs][0] = ld8(&P[(qs * 16 + lr) * SP + lq * 8]);
      pf[qs][1] = ld8(&P[(qs * 16 + lr) * SP + 32 + lq * 8]);
    }
#pragma unroll
    for (int qs = 0; qs < 4; ++qs) {
      lacc[qs] = mfma16(pf[qs][0], ones, lacc[qs]);
      lacc[qs] = mfma16(pf[qs][1], ones, lacc[qs]);
    }
#pragma unroll
    for (int j0 = 0; j0 < 4; ++j0) {
      const bf16* vrow = vbase + (long)(j0 * 16 + lr) * 1024 + kb * 64;
      bf16x8 vf0 = ld8(vrow + lq * 8);
      bf16x8 vf1 = ld8(vrow + 32 + lq * 8);
#pragma unroll
      for (int qs = 0; qs < 4; ++qs) {
        oacc[qs][j0] = mfma16(pf[qs][0], vf0, oacc[qs][j0]);
        oacc[qs][j0] = mfma16(pf[qs][1], vf1, oacc[qs][j0]);
      }
    }
    __builtin_amdgcn_sched_barrier(0);
  }

#pragma unroll
  for (int qs = 0; qs < 4; ++qs)
#pragma unroll
    for (int rr = 0; rr < 4; ++rr) {
      float lv = 1.0f / lacc[qs][rr];
#pragma unroll
      for (int j0 = 0; j0 < 4; ++j0)
        O[(long)(b * 1024 + q0 + qs * 16 + lq * 4 + rr) * 512 + h * 64 + j0 * 16 + lr] =
            __float2bfloat16(oacc[qs][j0][rr] * lv);
    }
}

// ---------------- fused residual + LayerNorm: one WAVE per row (D=512) ------------
template <typename TO>
__global__ __launch_bounds__(256) void add_ln_kernel(
    const bf16* __restrict__ X, const bf16* __restrict__ Y,
    const float* __restrict__ g, const float* __restrict__ bb,
    TO* __restrict__ out) {
  const int lane = threadIdx.x & 63, wave = threadIdx.x >> 6;
  const long row = (long)blockIdx.x * 4 + wave;
  const long base = row * 512 + lane * 8;
  bf16x8 xv = ld8(X + base);
  bf16x8 yv = ld8(Y + base);
  float v[8];
  float s = 0.f, q = 0.f;
#pragma unroll
  for (int k = 0; k < 8; ++k) {
    v[k] = (float)xv[k] + (float)yv[k];
    s += v[k];
    q += v[k] * v[k];
  }
#pragma unroll
  for (int o = 32; o > 0; o >>= 1) {
    s += __shfl_down(s, o);
    q += __shfl_down(q, o);
  }
  s = __shfl(s, 0);
  q = __shfl(q, 0);
  float mean = s * (1.f / 512.f);
  float var = q * (1.f / 512.f) - mean * mean;
  float rs = rsqrtf(var + 1e-5f);
  f32x4 g0 = *reinterpret_cast<const f32x4*>(&g[lane * 8]);
  f32x4 g1 = *reinterpret_cast<const f32x4*>(&g[lane * 8 + 4]);
  f32x4 b0 = *reinterpret_cast<const f32x4*>(&bb[lane * 8]);
  f32x4 b1 = *reinterpret_cast<const f32x4*>(&bb[lane * 8 + 4]);
  float r[8];
#pragma unroll
  for (int k = 0; k < 4; ++k) {
    r[k]     = (v[k]     - mean) * rs * g0[k] + b0[k];
    r[k + 4] = (v[k + 4] - mean) * rs * g1[k] + b1[k];
  }
  if constexpr (sizeof(TO) == 2) {
    bf16x8 o;
#pragma unroll
    for (int k = 0; k < 8; ++k) o[k] = __float2bfloat16(r[k]);
    *reinterpret_cast<bf16x8*>(&out[base]) = o;
  } else {
    f32x4 o0, o1;
#pragma unroll
    for (int k = 0; k < 4; ++k) { o0[k] = r[k]; o1[k] = r[k + 4]; }
    *reinterpret_cast<f32x4*>(&out[base]) = o0;
    *reinterpret_cast<f32x4*>(&out[base + 4]) = o1;
  }
}

// ---------------- launch ----------------
extern "C" void kernel_launch(void* const* d_in, const int* in_sizes, int n_in,
                              void* d_out, int out_size, void* d_ws, size_t ws_size,
                              hipStream_t stream) {
  const float* x    = (const float*)d_in[0];
  const float* Wq   = (const float*)d_in[1];
  const float* bq   = (const float*)d_in[2];
  const float* Wk   = (const float*)d_in[3];
  const float* bk   = (const float*)d_in[4];
  const float* Wv   = (const float*)d_in[5];
  const float* bv   = (const float*)d_in[6];
  const float* Wo   = (const float*)d_in[7];
  const float* bo   = (const float*)d_in[8];
  const float* ln1g = (const float*)d_in[9];
  const float* ln1b = (const float*)d_in[10];
  const float* W1   = (const float*)d_in[11];
  const float* b1   = (const float*)d_in[12];
  const float* W2   = (const float*)d_in[13];
  const float* b2   = (const float*)d_in[14];
  const float* ln2g = (const float*)d_in[15];
  const float* ln2b = (const float*)d_in[16];
  float* out = (float*)d_out;

  char* ws = (char*)d_ws;
  size_t off = 0;
  auto alloc = [&](size_t bytes) {
    char* p = ws + off;
    off += (bytes + 255) & ~(size_t)255;
    return (bf16*)p;
  };
  bf16* Wtqkv = alloc((size_t)1536 * 512 * 2);
  bf16* WtO   = alloc((size_t)512 * 512 * 2);
  bf16* Wt1   = alloc((size_t)512 * 2048 * 2);
  bf16* Wt2   = alloc((size_t)2048 * 512 * 2);
  float* bqs  = (float*)alloc((size_t)512 * 4);
  const size_t SB = (size_t)16384 * 512 * 2;  // 16 MB

  dim3 tb(32, 8);

  if (ws_size >= (size_t)104 * 1024 * 1024) {
    bf16* xb  = alloc(SB);
    bf16* kb  = alloc(SB);
    bf16* qb  = alloc(SB);
    bf16* vtb = alloc(SB);
    bf16* p0  = alloc(SB);
    bf16* p1  = alloc(SB);
    bf16* ff1 = qb;   // 64 MB contiguous qb|vtb|p0|p1
    bf16* ff2 = xb;
    (void)p0; (void)p1;

    cvt_prep<<<11265, tb, 0, stream>>>(x, xb, Wq, Wk, Wv, Wo, W1, W2, bq, bqs,
                                       Wtqkv, WtO, Wt1, Wt2);
    gemm_qkv<<<1536, 256, 0, stream>>>(xb, Wtqkv, Wtqkv + (size_t)1024 * 512,
                                       bqs, bk, bv, qb, kb, vtb);
    attn_fused<<<1024, 256, 0, stream>>>(qb, kb, vtb, qb);  // in-place: O -> qb
    gemm_kernel<0><<<512, 256, 0, stream>>>(qb, WtO, bo, nullptr, nullptr,
                                            vtb, nullptr, nullptr, 512, 512, 127, 7);
    add_ln_kernel<bf16><<<4096, 256, 0, stream>>>(xb, vtb, ln1g, ln1b, kb);
    gemm_kernel<1><<<2048, 256, 0, stream>>>(kb, Wt1, b1, nullptr, nullptr,
                                             ff1, nullptr, nullptr, 512, 2048, 127, 7);
    gemm_kernel<0><<<512, 256, 0, stream>>>(ff1, Wt2, b2, nullptr, nullptr,
                                            ff2, nullptr, nullptr, 2048, 512, 127, 7);
    add_ln_kernel<float><<<4096, 256, 0, stream>>>(kb, ff2, ln2g, ln2b, out);
  } else {
    bf16* xb  = alloc(SB);
    bf16* kb  = alloc(SB);       // K, then x1
    bf16* qb  = alloc(SB);       // Q, then O, then ff1 lo
    bf16* vtb = alloc(SB);       // Vt, then att, then ff1 hi
    bf16* fb  = alloc(SB / 2);   // ff2 half
    bf16* ff1 = qb;              // 32MB contiguous qb+vtb

    cvt_kernel<<<8192, 256, 0, stream>>>(x, xb);
    prep_weights<<<3072, tb, 0, stream>>>(Wq, Wk, Wv, Wo, W1, W2, bq, bqs,
                                          Wtqkv, WtO, Wt1, Wt2);
    gemm_kernel<2><<<1024, 256, 0, stream>>>(xb, Wtqkv, bqs, bk, nullptr,
                                             qb, kb, nullptr, 512, 512, 127, 7);
    gemm_kernel<3><<<512, 256, 0, stream>>>(xb, Wtqkv + (size_t)1024 * 512, bv,
                                            nullptr, nullptr, vtb, nullptr, nullptr,
                                            512, 512, 127, 7);
    attn_kernel<<<512, 256, 0, stream>>>(qb, kb, vtb, qb);
    gemm_kernel<0><<<512, 256, 0, stream>>>(qb, WtO, bo, nullptr, nullptr,
                                            vtb, nullptr, nullptr, 512, 512, 127, 7);
    add_ln_kernel<bf16><<<4096, 256, 0, stream>>>(xb, vtb, ln1g, ln1b, kb);

    for (int hh = 0; hh < 2; ++hh) {
      const bf16* x1h = kb + (size_t)hh * 8192 * 512;
      gemm_kernel<1><<<1024, 256, 0, stream>>>(x1h, Wt1, b1, nullptr, nullptr,
                                               ff1, nullptr, nullptr, 512, 2048, 63, 6);
      gemm_kernel<0><<<256, 256, 0, stream>>>(ff1, Wt2, b2, nullptr, nullptr,
                                              fb, nullptr, nullptr, 2048, 512, 63, 6);
      add_ln_kernel<float><<<2048, 256, 0, stream>>>(x1h, fb, ln2g, ln2b,
                                                     out + (size_t)hh * 8192 * 512);
    }
  }
}

// Round 17
// 349.833 us; speedup vs baseline: 1.0255x; 1.0255x over previous
//
#include <hip/hip_runtime.h>
#include <hip/hip_bf16.h>

typedef __hip_bfloat16 bf16;
typedef __bf16 bf16x8 __attribute__((ext_vector_type(8)));
typedef __bf16 bf16x4 __attribute__((ext_vector_type(4)));
typedef float f32x4 __attribute__((ext_vector_type(4)));

static __device__ __forceinline__ f32x4 mfma16(bf16x8 a, bf16x8 b, f32x4 c) {
  return __builtin_amdgcn_mfma_f32_16x16x32_bf16(a, b, c, 0, 0, 0);
}
static __device__ __forceinline__ bf16x8 ld8(const bf16* p) {
  return *reinterpret_cast<const bf16x8*>(p);
}
// raw v_exp_f32 (2^x): skips libm's denorm-guard; flush-to-zero for very
// negative args is exactly right for softmax numerators.
static __device__ __forceinline__ float fexp2(float x) {
#if __has_builtin(__builtin_amdgcn_exp2f)
  return __builtin_amdgcn_exp2f(x);
#else
  return exp2f(x);
#endif
}

typedef __attribute__((address_space(1))) void gvoid;
typedef __attribute__((address_space(3))) void lvoid;
static __device__ __forceinline__ void gl2lds16(const bf16* g, bf16* l) {
  __builtin_amdgcn_global_load_lds((gvoid*)g, (lvoid*)l, 16, 0, 0);
}

#define CC_SCALE 0.18033688011112042f  // (1/8)*log2(e), folded into Wq/bq

// Bank-conflict fix (T2 via pre-swizzled SOURCE, rule #21):
// chunk' = chunk ^ ((row>>1)&3); writer: (lane&3)^((lane>>3)&3); reader: lq^((lr>>1)&3).
// GELU note: erff is FINAL. Three epilogue-GELU variants (R7/R10/R15) all
// inflated VGPR 76->88/92 via interleaved exp live-ranges and lost more to
// occupancy than the VALU saving (R15: VALUBusy 38->25.6 but dur +1.8us).

// ---------------- fused fp32->bf16 cvt + ALL weight transposes, ONE dispatch -------
__global__ __launch_bounds__(256) void cvt_prep(
    const float* __restrict__ x, bf16* __restrict__ xb,
    const float* __restrict__ Wq, const float* __restrict__ Wk,
    const float* __restrict__ Wv, const float* __restrict__ Wo,
    const float* __restrict__ W1, const float* __restrict__ W2,
    const float* __restrict__ bq, float* __restrict__ bqs,
    bf16* __restrict__ Wtqkv, bf16* __restrict__ WtO,
    bf16* __restrict__ Wt1, bf16* __restrict__ Wt2) {
  int blk = blockIdx.x;
  int tx = threadIdx.x, ty = threadIdx.y;
  if (blk < 8192) {
    int t = ty * 32 + tx;
    long i = (long)blk * 256 + t;
    float4 v = reinterpret_cast<const float4*>(x)[i];
    bf16x4 o;
    o[0] = __float2bfloat16(v.x); o[1] = __float2bfloat16(v.y);
    o[2] = __float2bfloat16(v.z); o[3] = __float2bfloat16(v.w);
    reinterpret_cast<bf16x4*>(xb)[i] = o;
    return;
  }
  if (blk == 11264) {  // bq scale tail
    int t = ty * 32 + tx;
    bqs[t] = bq[t] * CC_SCALE;
    bqs[t + 256] = bq[t + 256] * CC_SCALE;
    return;
  }
  int id = blk - 8192;
  const float* in;
  bf16* out;
  int K, N, n0, k0;
  float scl = 1.0f;
  if (id < 1024) {
    int which = id >> 8, t = id & 255;
    K = 512; N = 512;
    n0 = (t & 15) * 32; k0 = (t >> 4) * 32;
    if (which == 0)      { in = Wq; out = Wtqkv; scl = CC_SCALE; }
    else if (which == 1) { in = Wk; out = Wtqkv + (size_t)512 * 512; }
    else if (which == 2) { in = Wv; out = Wtqkv + (size_t)1024 * 512; }
    else                 { in = Wo; out = WtO; }
  } else if (id < 2048) {
    int t = id - 1024;
    in = W1; out = Wt1; K = 512; N = 2048;
    n0 = (t & 63) * 32; k0 = (t >> 6) * 32;
  } else {
    int t = id - 2048;
    in = W2; out = Wt2; K = 2048; N = 512;
    n0 = (t & 15) * 32; k0 = (t >> 4) * 32;
  }
  __shared__ float tile[32][33];
#pragma unroll
  for (int j = 0; j < 32; j += 8)
    tile[ty + j][tx] = in[(long)(k0 + ty + j) * N + n0 + tx];
  __syncthreads();
#pragma unroll
  for (int j = 0; j < 32; j += 8)
    out[(long)(n0 + ty + j) * K + k0 + tx] = __float2bfloat16(tile[tx][ty + j] * scl);
}

// ---------------- standalone kernels (fallback path) ----------------
__global__ __launch_bounds__(256) void cvt_kernel(const float* __restrict__ in,
                                                  bf16* __restrict__ out) {
  long i = (long)blockIdx.x * 256 + threadIdx.x;
  float4 v = reinterpret_cast<const float4*>(in)[i];
  bf16x4 o;
  o[0] = __float2bfloat16(v.x); o[1] = __float2bfloat16(v.y);
  o[2] = __float2bfloat16(v.z); o[3] = __float2bfloat16(v.w);
  reinterpret_cast<bf16x4*>(out)[i] = o;
}

__global__ void prep_weights(const float* __restrict__ Wq, const float* __restrict__ Wk,
                             const float* __restrict__ Wv, const float* __restrict__ Wo,
                             const float* __restrict__ W1, const float* __restrict__ W2,
                             const float* __restrict__ bq, float* __restrict__ bqs,
                             bf16* __restrict__ Wtqkv, bf16* __restrict__ WtO,
                             bf16* __restrict__ Wt1, bf16* __restrict__ Wt2) {
  int id = blockIdx.x;
  int tx = threadIdx.x, ty = threadIdx.y;
  if (id == 0) {
    int t = ty * 32 + tx;
    bqs[t] = bq[t] * CC_SCALE;
    bqs[t + 256] = bq[t + 256] * CC_SCALE;
  }
  const float* in;
  bf16* out;
  int K, N, n0, k0;
  float scl = 1.0f;
  if (id < 1024) {
    int which = id >> 8, t = id & 255;
    K = 512; N = 512;
    n0 = (t & 15) * 32; k0 = (t >> 4) * 32;
    if (which == 0)      { in = Wq; out = Wtqkv; scl = CC_SCALE; }
    else if (which == 1) { in = Wk; out = Wtqkv + (size_t)512 * 512; }
    else if (which == 2) { in = Wv; out = Wtqkv + (size_t)1024 * 512; }
    else                 { in = Wo; out = WtO; }
  } else if (id < 2048) {
    int t = id - 1024;
    in = W1; out = Wt1; K = 512; N = 2048;
    n0 = (t & 63) * 32; k0 = (t >> 6) * 32;
  } else {
    int t = id - 2048;
    in = W2; out = Wt2; K = 2048; N = 512;
    n0 = (t & 15) * 32; k0 = (t >> 4) * 32;
  }
  __shared__ float tile[32][33];
#pragma unroll
  for (int j = 0; j < 32; j += 8)
    tile[ty + j][tx] = in[(long)(k0 + ty + j) * N + n0 + tx];
  __syncthreads();
#pragma unroll
  for (int j = 0; j < 32; j += 8)
    out[(long)(n0 + ty + j) * K + k0 + tx] = __float2bfloat16(tile[tx][ty + j] * scl);
}

// ---------------- 128^2 MFMA GEMM: 3-buffer ring, counted vmcnt, XOR-swizzled LDS --
template <int MODE>
__global__ __launch_bounds__(256) void gemm_kernel(
    const bf16* __restrict__ A, const bf16* __restrict__ Wt,
    const float* __restrict__ b0, const float* __restrict__ b1_,
    const float* __restrict__ b2_, bf16* C0, bf16* C1, bf16* C2,
    int K, int ldc, int mmask, int mshift) {
  __shared__ alignas(16) bf16 As[3][128 * 32];
  __shared__ alignas(16) bf16 Bs[3][128 * 32];
  const int tid = threadIdx.x;
  const int wave = tid >> 6, lane = tid & 63;
  const int lr = lane & 15, lq = lane >> 4;
  const int L = blockIdx.x;
  const int m0 = (L & mmask) * 128, n0 = (L >> mshift) * 128;
  const int wm = (wave >> 1) * 64, wn = (wave & 1) * 64;

  const int srow0 = (wave * 2) * 16 + (lane >> 2);
  const int srow1 = (wave * 2 + 1) * 16 + (lane >> 2);
  const int scol = (((lane & 3) ^ ((lane >> 3) & 3))) * 8;
  const bf16* Ag0 = A + (long)(m0 + srow0) * K + scol;
  const bf16* Ag1 = A + (long)(m0 + srow1) * K + scol;
  const bf16* Bg0 = Wt + (long)(n0 + srow0) * K + scol;
  const bf16* Bg1 = Wt + (long)(n0 + srow1) * K + scol;
  const int so0 = (wave * 2) * 16 * 32;
  const int so1 = (wave * 2 + 1) * 16 * 32;
  const int xr = (lr >> 1) & 3;

  f32x4 acc[4][4] = {};

  auto stage = [&](int k0, int buf) {
    gl2lds16(Ag0 + k0, &As[buf][so0]);
    gl2lds16(Ag1 + k0, &As[buf][so1]);
    gl2lds16(Bg0 + k0, &Bs[buf][so0]);
    gl2lds16(Bg1 + k0, &Bs[buf][so1]);
  };

  stage(0, 0);
  stage(32, 1);

  const int nk = K >> 5;
  int cur = 0, sb = 2;
  for (int t = 0; t < nk; ++t) {
    if (t < nk - 1) {
      asm volatile("s_waitcnt vmcnt(4)" ::: "memory");
    } else {
      asm volatile("s_waitcnt vmcnt(0)" ::: "memory");
    }
    __builtin_amdgcn_s_barrier();
    if (t < nk - 2) stage((t + 2) << 5, sb);

    bf16x8 af[4], bfr[4];
#pragma unroll
    for (int i = 0; i < 4; ++i)
      af[i] = ld8(&As[cur][(wm + i * 16 + lr) * 32 + (lq ^ xr) * 8]);
#pragma unroll
    for (int j = 0; j < 4; ++j)
      bfr[j] = ld8(&Bs[cur][(wn + j * 16 + lr) * 32 + (lq ^ xr) * 8]);
    if constexpr (MODE == 3) {
#pragma unroll
      for (int i = 0; i < 4; ++i)
#pragma unroll
        for (int j = 0; j < 4; ++j) acc[i][j] = mfma16(af[i], bfr[j], acc[i][j]);
    } else {
#pragma unroll
      for (int i = 0; i < 4; ++i)
#pragma unroll
        for (int j = 0; j < 4; ++j) acc[i][j] = mfma16(bfr[j], af[i], acc[i][j]);
    }

    cur = (cur == 2) ? 0 : cur + 1;
    sb = (sb == 2) ? 0 : sb + 1;
  }

  if constexpr (MODE == 3) {
#pragma unroll
    for (int i = 0; i < 4; ++i) {
      int row0 = m0 + wm + i * 16 + lq * 4;
      int bb = row0 >> 10, tok = row0 & 1023;
#pragma unroll
      for (int j = 0; j < 4; ++j) {
        int col = n0 + wn + j * 16 + lr;
        float bv = b0[col];
        int hh = col >> 6, e = col & 63;
        bf16x4 o;
#pragma unroll
        for (int rr = 0; rr < 4; ++rr) o[rr] = __float2bfloat16(acc[i][j][rr] + bv);
        *reinterpret_cast<bf16x4*>(
            &C0[(((long)((bb * 8 + hh) * 64 + e)) << 10) + tok]) = o;
      }
    }
  } else {
    const float* bias = b0;
    bf16* C = C0;
    int cb = n0;
    if (MODE == 2 && n0 >= 512) { bias = b1_; C = C1; cb = n0 - 512; }
#pragma unroll
    for (int i = 0; i < 4; ++i) {
      int row = m0 + wm + i * 16 + lr;
      long rb = (long)row * ldc;
#pragma unroll
      for (int j = 0; j < 4; ++j) {
        int col0 = cb + wn + j * 16 + lq * 4;
        f32x4 bv = *reinterpret_cast<const f32x4*>(&bias[col0]);
        bf16x4 o;
#pragma unroll
        for (int rr = 0; rr < 4; ++rr) {
          float v = acc[i][j][rr] + bv[rr];
          if (MODE == 1) v = 0.5f * v * (1.0f + erff(v * 0.70710678118654752f));
          o[rr] = __float2bfloat16(v);
        }
        *reinterpret_cast<bf16x4*>(&C[rb + col0]) = o;
      }
    }
  }
}

// ---------------- merged QKV: Q/K (swapped) + V (unswapped) in ONE dispatch --------
__global__ __launch_bounds__(256) void gemm_qkv(
    const bf16* __restrict__ A, const bf16* __restrict__ Wqk,
    const bf16* __restrict__ Wv, const float* __restrict__ bqs,
    const float* __restrict__ bk, const float* __restrict__ bv,
    bf16* __restrict__ Qo, bf16* __restrict__ Ko, bf16* __restrict__ Vt) {
  __shared__ alignas(16) bf16 As[3][128 * 32];
  __shared__ alignas(16) bf16 Bs[3][128 * 32];
  const int tid = threadIdx.x;
  const int wave = tid >> 6, lane = tid & 63;
  const int lr = lane & 15, lq = lane >> 4;
  const int L = blockIdx.x;
  const bool vmode = L >= 1024;
  const int Lx = vmode ? L - 1024 : L;
  const bf16* Wt = vmode ? Wv : Wqk;
  const int m0 = (Lx & 127) * 128, n0 = (Lx >> 7) * 128;
  const int wm = (wave >> 1) * 64, wn = (wave & 1) * 64;
  const int K = 512;

  const int srow0 = (wave * 2) * 16 + (lane >> 2);
  const int srow1 = (wave * 2 + 1) * 16 + (lane >> 2);
  const int scol = (((lane & 3) ^ ((lane >> 3) & 3))) * 8;
  const bf16* Ag0 = A + (long)(m0 + srow0) * K + scol;
  const bf16* Ag1 = A + (long)(m0 + srow1) * K + scol;
  const bf16* Bg0 = Wt + (long)(n0 + srow0) * K + scol;
  const bf16* Bg1 = Wt + (long)(n0 + srow1) * K + scol;
  const int so0 = (wave * 2) * 16 * 32;
  const int so1 = (wave * 2 + 1) * 16 * 32;
  const int xr = (lr >> 1) & 3;

  f32x4 acc[4][4] = {};

  auto stage = [&](int k0, int buf) {
    gl2lds16(Ag0 + k0, &As[buf][so0]);
    gl2lds16(Ag1 + k0, &As[buf][so1]);
    gl2lds16(Bg0 + k0, &Bs[buf][so0]);
    gl2lds16(Bg1 + k0, &Bs[buf][so1]);
  };

  stage(0, 0);
  stage(32, 1);

  const int nk = K >> 5;  // 16
  int cur = 0, sb = 2;
  if (!vmode) {
    for (int t = 0; t < nk; ++t) {
      if (t < nk - 1) {
        asm volatile("s_waitcnt vmcnt(4)" ::: "memory");
      } else {
        asm volatile("s_waitcnt vmcnt(0)" ::: "memory");
      }
      __builtin_amdgcn_s_barrier();
      if (t < nk - 2) stage((t + 2) << 5, sb);
      bf16x8 af[4], bfr[4];
#pragma unroll
      for (int i = 0; i < 4; ++i)
        af[i] = ld8(&As[cur][(wm + i * 16 + lr) * 32 + (lq ^ xr) * 8]);
#pragma unroll
      for (int j = 0; j < 4; ++j)
        bfr[j] = ld8(&Bs[cur][(wn + j * 16 + lr) * 32 + (lq ^ xr) * 8]);
#pragma unroll
      for (int i = 0; i < 4; ++i)
#pragma unroll
        for (int j = 0; j < 4; ++j) acc[i][j] = mfma16(bfr[j], af[i], acc[i][j]);
      cur = (cur == 2) ? 0 : cur + 1;
      sb = (sb == 2) ? 0 : sb + 1;
    }
    const float* bias = bqs;
    bf16* C = Qo;
    int cb = n0;
    if (n0 >= 512) { bias = bk; C = Ko; cb = n0 - 512; }
#pragma unroll
    for (int i = 0; i < 4; ++i) {
      int row = m0 + wm + i * 16 + lr;
      long rb = (long)row * 512;
#pragma unroll
      for (int j = 0; j < 4; ++j) {
        int col0 = cb + wn + j * 16 + lq * 4;
        f32x4 bv = *reinterpret_cast<const f32x4*>(&bias[col0]);
        bf16x4 o;
#pragma unroll
        for (int rr = 0; rr < 4; ++rr)
          o[rr] = __float2bfloat16(acc[i][j][rr] + bv[rr]);
        *reinterpret_cast<bf16x4*>(&C[rb + col0]) = o;
      }
    }
  } else {
    for (int t = 0; t < nk; ++t) {
      if (t < nk - 1) {
        asm volatile("s_waitcnt vmcnt(4)" ::: "memory");
      } else {
        asm volatile("s_waitcnt vmcnt(0)" ::: "memory");
      }
      __builtin_amdgcn_s_barrier();
      if (t < nk - 2) stage((t + 2) << 5, sb);
      bf16x8 af[4], bfr[4];
#pragma unroll
      for (int i = 0; i < 4; ++i)
        af[i] = ld8(&As[cur][(wm + i * 16 + lr) * 32 + (lq ^ xr) * 8]);
#pragma unroll
      for (int j = 0; j < 4; ++j)
        bfr[j] = ld8(&Bs[cur][(wn + j * 16 + lr) * 32 + (lq ^ xr) * 8]);
#pragma unroll
      for (int i = 0; i < 4; ++i)
#pragma unroll
        for (int j = 0; j < 4; ++j) acc[i][j] = mfma16(af[i], bfr[j], acc[i][j]);
      cur = (cur == 2) ? 0 : cur + 1;
      sb = (sb == 2) ? 0 : sb + 1;
    }
#pragma unroll
    for (int i = 0; i < 4; ++i) {
      int row0 = m0 + wm + i * 16 + lq * 4;
      int bb = row0 >> 10, tok = row0 & 1023;
#pragma unroll
      for (int j = 0; j < 4; ++j) {
        int col = n0 + wn + j * 16 + lr;
        float bvv = bv[col];
        int hh = col >> 6, e = col & 63;
        bf16x4 o;
#pragma unroll
        for (int rr = 0; rr < 4; ++rr) o[rr] = __float2bfloat16(acc[i][j][rr] + bvv);
        *reinterpret_cast<bf16x4*>(
            &Vt[(((long)((bb * 8 + hh) * 64 + e)) << 10) + tok]) = o;
      }
    }
  }
}

// ---------------- fused flash attention: LDS-staged K/V (swizzled), 32 q/wave ------
__global__ __launch_bounds__(256) void attn_fused(
    const bf16* __restrict__ Q, const bf16* __restrict__ Km,
    const bf16* __restrict__ Vt, bf16* __restrict__ O) {
  constexpr int SP = 72;
  __shared__ alignas(16) bf16 Pall[4][32 * SP];
  __shared__ alignas(16) bf16 Ks[2][2][64][32];
  __shared__ alignas(16) bf16 Vs[2][2][64][32];
  const int tid = threadIdx.x;
  const int wave = tid >> 6, lane = tid & 63;
  const int lr = lane & 15, lq = lane >> 4;
  const int L = blockIdx.x;
  const int bh = ((L >> 6) << 3) | (L & 7);   // same bh -> same XCD
  const int qc = (L >> 3) & 7;
  const int h = bh & 7, b = bh >> 3;
  const int q0 = qc * 128 + wave * 32;
  bf16* P = Pall[wave];

  bf16x8 qf[2][2];
#pragma unroll
  for (int qs = 0; qs < 2; ++qs) {
    const bf16* qrow = Q + (long)(b * 1024 + q0 + qs * 16 + lr) * 512 + h * 64;
    qf[qs][0] = ld8(qrow + lq * 8);
    qf[qs][1] = ld8(qrow + 32 + lq * 8);
  }
  const bf16* kbase = Km + (long)(b * 1024) * 512 + h * 64;
  const bf16* vbase = Vt + (long)((b * 8 + h) * 64) * 1024;

  const int sr = wave * 16 + (lane >> 2);
  const int sc = (((lane & 3) ^ ((lane >> 3) & 3))) * 8;
  const bf16* Kg = kbase + (long)sr * 512 + sc;
  const bf16* Vg = vbase + (long)sr * 1024 + sc;
  const int xr = (lr >> 1) & 3;

  auto stage = [&](int kb, int p) {
#pragma unroll
    for (int kk = 0; kk < 2; ++kk)
      gl2lds16(Kg + (long)kb * 64 * 512 + kk * 32, &Ks[p][kk][wave * 16][0]);
#pragma unroll
    for (int kk = 0; kk < 2; ++kk)
      gl2lds16(Vg + kb * 64 + kk * 32, &Vs[p][kk][wave * 16][0]);
  };

  bf16x8 ones;
#pragma unroll
  for (int k = 0; k < 8; ++k) ones[k] = __float2bfloat16(1.0f);

  f32x4 oacc[2][4] = {};
  f32x4 lacc[2] = {};

  stage(0, 0);
  __syncthreads();

  int p = 0;
  for (int kb = 0; kb < 16; ++kb) {
    if (kb < 15) stage(kb + 1, p ^ 1);  // block-uniform; drained by end barrier
#pragma unroll
    for (int kt = 0; kt < 4; ++kt) {
      bf16x8 kf0 = ld8(&Ks[p][0][kt * 16 + lr][(lq ^ xr) * 8]);
      bf16x8 kf1 = ld8(&Ks[p][1][kt * 16 + lr][(lq ^ xr) * 8]);
#pragma unroll
      for (int qs = 0; qs < 2; ++qs) {
        f32x4 t = {};
        t = mfma16(kf0, qf[qs][0], t);
        t = mfma16(kf1, qf[qs][1], t);
        bf16x4 pk;
#pragma unroll
        for (int rr = 0; rr < 4; ++rr) pk[rr] = __float2bfloat16(fexp2(t[rr]));
        *reinterpret_cast<bf16x4*>(&P[(qs * 16 + lr) * SP + kt * 16 + lq * 4]) = pk;
      }
    }
    __builtin_amdgcn_sched_barrier(0);  // P writes before P reads; caps VGPR
    bf16x8 pf[2][2];
#pragma unroll
    for (int qs = 0; qs < 2; ++qs) {
      pf[qs][0] = ld8(&P[(qs * 16 + lr) * SP + lq * 8]);
      pf[qs][1] = ld8(&P[(qs * 16 + lr) * SP + 32 + lq * 8]);
    }
#pragma unroll
    for (int qs = 0; qs < 2; ++qs) {
      lacc[qs] = mfma16(ones, pf[qs][0], lacc[qs]);   // l(q=lr) in every slot
      lacc[qs] = mfma16(ones, pf[qs][1], lacc[qs]);
    }
#pragma unroll
    for (int j0 = 0; j0 < 4; ++j0) {
      bf16x8 vf0 = ld8(&Vs[p][0][j0 * 16 + lr][(lq ^ xr) * 8]);
      bf16x8 vf1 = ld8(&Vs[p][1][j0 * 16 + lr][(lq ^ xr) * 8]);
#pragma unroll
      for (int qs = 0; qs < 2; ++qs) {
        oacc[qs][j0] = mfma16(vf0, pf[qs][0], oacc[qs][j0]);  // swapped: col=q
        oacc[qs][j0] = mfma16(vf1, pf[qs][1], oacc[qs][j0]);
      }
    }
    __builtin_amdgcn_sched_barrier(0);  // P reads before next iter's P writes
    __syncthreads();  // drains vmcnt: buf p^1 staged; readers of buf p done
    p ^= 1;
  }

  // lane holds O[q = q0+qs*16+lr][e = j0*16 + lq*4 + rr]
#pragma unroll
  for (int qs = 0; qs < 2; ++qs) {
    float lv = 1.0f / lacc[qs][0];
    bf16* orow = O + (long)(b * 1024 + q0 + qs * 16 + lr) * 512 + h * 64 + lq * 4;
#pragma unroll
    for (int j0 = 0; j0 < 4; ++j0) {
      bf16x4 o;
#pragma unroll
      for (int rr = 0; rr < 4; ++rr) o[rr] = __float2bfloat16(oacc[qs][j0][rr] * lv);
      *reinterpret_cast<bf16x4*>(&orow[j0 * 16]) = o;
    }
  }
}

// ---------------- fallback attention (Q pre-scaled) ----------------
__global__ __launch_bounds__(256) void attn_kernel(
    const bf16* Q, const bf16* __restrict__ Km,
    const bf16* __restrict__ Vt, bf16* O) {
  constexpr int SP = 72;
  __shared__ alignas(16) bf16 Pall[4][64 * SP];
  const int tid = threadIdx.x;
  const int wave = tid >> 6, lane = tid & 63;
  const int lr = lane & 15, lq = lane >> 4;
  const int L = blockIdx.x;
  const int bh = ((L >> 5) << 3) | (L & 7);
  const int qc = (L >> 3) & 3;
  const int h = bh & 7, b = bh >> 3;
  const int q0 = qc * 256 + wave * 64;
  bf16* P = Pall[wave];

  bf16x8 qf[4][2];
#pragma unroll
  for (int qs = 0; qs < 4; ++qs) {
    const bf16* qrow = Q + (long)(b * 1024 + q0 + qs * 16 + lr) * 512 + h * 64;
    qf[qs][0] = ld8(qrow + lq * 8);
    qf[qs][1] = ld8(qrow + 32 + lq * 8);
  }
  const bf16* kbase = Km + (long)(b * 1024) * 512 + h * 64;
  const bf16* vbase = Vt + (long)((b * 8 + h) * 64) * 1024;

  bf16x8 ones;
#pragma unroll
  for (int k = 0; k < 8; ++k) ones[k] = __float2bfloat16(1.0f);

  f32x4 oacc[4][4] = {};
  f32x4 lacc[4] = {};

  for (int kb = 0; kb < 16; ++kb) {
#pragma unroll
    for (int kt = 0; kt < 4; ++kt) {
      const bf16* krow = kbase + (long)(kb * 64 + kt * 16 + lr) * 512;
      bf16x8 kf0 = ld8(krow + lq * 8);
      bf16x8 kf1 = ld8(krow + 32 + lq * 8);
#pragma unroll
      for (int qs = 0; qs < 4; ++qs) {
        f32x4 t = {};
        t = mfma16(kf0, qf[qs][0], t);
        t = mfma16(kf1, qf[qs][1], t);
        bf16x4 pk;
#pragma unroll
        for (int rr = 0; rr < 4; ++rr) pk[rr] = __float2bfloat16(fexp2(t[rr]));
        *reinterpret_cast<bf16x4*>(&P[(qs * 16 + lr) * SP + kt * 16 + lq * 4]) = pk;
      }
    }
    __builtin_amdgcn_sched_barrier(0);
    bf16x8 pf[4][2];
#pragma unroll
    for (int qs = 0; qs < 4; ++qs) {
      pf[qs][0] = ld8(&P[(qs * 16 + lr) * SP + lq * 8]);
      pf[qs][1] = ld8(&P[(qs * 16 + lr) * SP + 32 + lq * 8]);
    }
#pragma unroll
    for (int qs = 0; qs < 4; ++qs) {
      lacc[qs] = mfma16(pf[qs][0], ones, lacc[qs]);
      lacc[qs] = mfma16(pf[qs][1], ones, lacc[qs]);
    }
#pragma unroll
    for (int j0 = 0; j0 < 4; ++j0) {
      const bf16* vrow = vbase + (long)(j0 * 16 + lr) * 1024 + kb * 64;
      bf16x8 vf0 = ld8(vrow + lq * 8);
      bf16x8 vf1 = ld8(vrow + 32 + lq * 8);
#pragma unroll
      for (int qs = 0; qs < 4; ++qs) {
        oacc[qs][j0] = mfma16(pf[qs][0], vf0, oacc[qs][j0]);
        oacc[qs][j0] = mfma16(pf[qs][1], vf1, oacc[qs][j0]);
      }
    }
    __builtin_amdgcn_sched_barrier(0);
  }

#pragma unroll
  for (int qs = 0; qs < 4; ++qs)
#pragma unroll
    for (int rr = 0; rr < 4; ++rr) {
      float lv = 1.0f / lacc[qs][rr];
#pragma unroll
      for (int j0 = 0; j0 < 4; ++j0)
        O[(long)(b * 1024 + q0 + qs * 16 + lq * 4 + rr) * 512 + h * 64 + j0 * 16 + lr] =
            __float2bfloat16(oacc[qs][j0][rr] * lv);
    }
}

// ---------------- fused residual + LayerNorm: one WAVE per row (D=512) ------------
template <typename TO>
__global__ __launch_bounds__(256) void add_ln_kernel(
    const bf16* __restrict__ X, const bf16* __restrict__ Y,
    const float* __restrict__ g, const float* __restrict__ bb,
    TO* __restrict__ out) {
  const int lane = threadIdx.x & 63, wave = threadIdx.x >> 6;
  const long row = (long)blockIdx.x * 4 + wave;
  const long base = row * 512 + lane * 8;
  bf16x8 xv = ld8(X + base);
  bf16x8 yv = ld8(Y + base);
  float v[8];
  float s = 0.f, q = 0.f;
#pragma unroll
  for (int k = 0; k < 8; ++k) {
    v[k] = (float)xv[k] + (float)yv[k];
    s += v[k];
    q += v[k] * v[k];
  }
#pragma unroll
  for (int o = 32; o > 0; o >>= 1) {
    s += __shfl_down(s, o);
    q += __shfl_down(q, o);
  }
  s = __shfl(s, 0);
  q = __shfl(q, 0);
  float mean = s * (1.f / 512.f);
  float var = q * (1.f / 512.f) - mean * mean;
  float rs = rsqrtf(var + 1e-5f);
  f32x4 g0 = *reinterpret_cast<const f32x4*>(&g[lane * 8]);
  f32x4 g1 = *reinterpret_cast<const f32x4*>(&g[lane * 8 + 4]);
  f32x4 b0 = *reinterpret_cast<const f32x4*>(&bb[lane * 8]);
  f32x4 b1 = *reinterpret_cast<const f32x4*>(&bb[lane * 8 + 4]);
  float r[8];
#pragma unroll
  for (int k = 0; k < 4; ++k) {
    r[k]     = (v[k]     - mean) * rs * g0[k] + b0[k];
    r[k + 4] = (v[k + 4] - mean) * rs * g1[k] + b1[k];
  }
  if constexpr (sizeof(TO) == 2) {
    bf16x8 o;
#pragma unroll
    for (int k = 0; k < 8; ++k) o[k] = __float2bfloat16(r[k]);
    *reinterpret_cast<bf16x8*>(&out[base]) = o;
  } else {
    f32x4 o0, o1;
#pragma unroll
    for (int k = 0; k < 4; ++k) { o0[k] = r[k]; o1[k] = r[k + 4]; }
    *reinterpret_cast<f32x4*>(&out[base]) = o0;
    *reinterpret_cast<f32x4*>(&out[base + 4]) = o1;
  }
}

// ---------------- launch ----------------
extern "C" void kernel_launch(void* const* d_in, const int* in_sizes, int n_in,
                              void* d_out, int out_size, void* d_ws, size_t ws_size,
                              hipStream_t stream) {
  const float* x    = (const float*)d_in[0];
  const float* Wq   = (const float*)d_in[1];
  const float* bq   = (const float*)d_in[2];
  const float* Wk   = (const float*)d_in[3];
  const float* bk   = (const float*)d_in[4];
  const float* Wv   = (const float*)d_in[5];
  const float* bv   = (const float*)d_in[6];
  const float* Wo   = (const float*)d_in[7];
  const float* bo   = (const float*)d_in[8];
  const float* ln1g = (const float*)d_in[9];
  const float* ln1b = (const float*)d_in[10];
  const float* W1   = (const float*)d_in[11];
  const float* b1   = (const float*)d_in[12];
  const float* W2   = (const float*)d_in[13];
  const float* b2   = (const float*)d_in[14];
  const float* ln2g = (const float*)d_in[15];
  const float* ln2b = (const float*)d_in[16];
  float* out = (float*)d_out;

  char* ws = (char*)d_ws;
  size_t off = 0;
  auto alloc = [&](size_t bytes) {
    char* p = ws + off;
    off += (bytes + 255) & ~(size_t)255;
    return (bf16*)p;
  };
  bf16* Wtqkv = alloc((size_t)1536 * 512 * 2);
  bf16* WtO   = alloc((size_t)512 * 512 * 2);
  bf16* Wt1   = alloc((size_t)512 * 2048 * 2);
  bf16* Wt2   = alloc((size_t)2048 * 512 * 2);
  float* bqs  = (float*)alloc((size_t)512 * 4);
  const size_t SB = (size_t)16384 * 512 * 2;  // 16 MB

  dim3 tb(32, 8);

  if (ws_size >= (size_t)104 * 1024 * 1024) {
    bf16* xb  = alloc(SB);
    bf16* kb  = alloc(SB);
    bf16* qb  = alloc(SB);
    bf16* vtb = alloc(SB);
    bf16* p0  = alloc(SB);
    bf16* p1  = alloc(SB);
    bf16* ff1 = qb;   // 64 MB contiguous qb|vtb|p0|p1
    bf16* ff2 = xb;
    (void)p0; (void)p1;

    cvt_prep<<<11265, tb, 0, stream>>>(x, xb, Wq, Wk, Wv, Wo, W1, W2, bq, bqs,
                                       Wtqkv, WtO, Wt1, Wt2);
    gemm_qkv<<<1536, 256, 0, stream>>>(xb, Wtqkv, Wtqkv + (size_t)1024 * 512,
                                       bqs, bk, bv, qb, kb, vtb);
    attn_fused<<<1024, 256, 0, stream>>>(qb, kb, vtb, qb);  // in-place: O -> qb
    gemm_kernel<0><<<512, 256, 0, stream>>>(qb, WtO, bo, nullptr, nullptr,
                                            vtb, nullptr, nullptr, 512, 512, 127, 7);
    add_ln_kernel<bf16><<<4096, 256, 0, stream>>>(xb, vtb, ln1g, ln1b, kb);
    gemm_kernel<1><<<2048, 256, 0, stream>>>(kb, Wt1, b1, nullptr, nullptr,
                                             ff1, nullptr, nullptr, 512, 2048, 127, 7);
    gemm_kernel<0><<<512, 256, 0, stream>>>(ff1, Wt2, b2, nullptr, nullptr,
                                            ff2, nullptr, nullptr, 2048, 512, 127, 7);
    add_ln_kernel<float><<<4096, 256, 0, stream>>>(kb, ff2, ln2g, ln2b, out);
  } else {
    bf16* xb  = alloc(SB);
    bf16* kb  = alloc(SB);       // K, then x1
    bf16* qb  = alloc(SB);       // Q, then O, then ff1 lo
    bf16* vtb = alloc(SB);       // Vt, then att, then ff1 hi
    bf16* fb  = alloc(SB / 2);   // ff2 half
    bf16* ff1 = qb;              // 32MB contiguous qb+vtb

    cvt_kernel<<<8192, 256, 0, stream>>>(x, xb);
    prep_weights<<<3072, tb, 0, stream>>>(Wq, Wk, Wv, Wo, W1, W2, bq, bqs,
                                          Wtqkv, WtO, Wt1, Wt2);
    gemm_kernel<2><<<1024, 256, 0, stream>>>(xb, Wtqkv, bqs, bk, nullptr,
                                             qb, kb, nullptr, 512, 512, 127, 7);
    gemm_kernel<3><<<512, 256, 0, stream>>>(xb, Wtqkv + (size_t)1024 * 512, bv,
                                            nullptr, nullptr, vtb, nullptr, nullptr,
                                            512, 512, 127, 7);
    attn_kernel<<<512, 256, 0, stream>>>(qb, kb, vtb, qb);
    gemm_kernel<0><<<512, 256, 0, stream>>>(qb, WtO, bo, nullptr, nullptr,
                                            vtb, nullptr, nullptr, 512, 512, 127, 7);
    add_ln_kernel<bf16><<<4096, 256, 0, stream>>>(xb, vtb, ln1g, ln1b, kb);

    for (int hh = 0; hh < 2; ++hh) {
      const bf16* x1h = kb + (size_t)hh * 8192 * 512;
      gemm_kernel<1><<<1024, 256, 0, stream>>>(x1h, Wt1, b1, nullptr, nullptr,
                                               ff1, nullptr, nullptr, 512, 2048, 63, 6);
      gemm_kernel<0><<<256, 256, 0, stream>>>(ff1, Wt2, b2, nullptr, nullptr,
                                              fb, nullptr, nullptr, 2048, 512, 63, 6);
      add_ln_kernel<float><<<2048, 256, 0, stream>>>(x1h, fb, ln2g, ln2b,
                                                     out + (size_t)hh * 8192 * 512);
    }
  }
}